// Round 7
// baseline (812.431 us; speedup 1.0000x reference)
//
#include <hip/hip_runtime.h>

#define N_NODES 100000
#define N_EDGES 1600000
#define IN_C 32
#define HID_C 64
#define OUT_C 32

#define EPB 1024                                 // edges per hist/place block
#define NBLK ((N_EDGES + EPB - 1) / EPB)         // 1563
#define BSH 8                                    // 256 nodes per bucket
#define BKN (1 << BSH)
#define NB ((N_NODES + BKN - 1) / BKN)           // 391
#define ACCS 33                                  // padded LDS row stride

// ---- pass A: per-block bucket histogram (LDS only; no global atomics) ---
__global__ __launch_bounds__(256) void bucket_hist_kernel(
    const int* __restrict__ dst, int* __restrict__ gh) {
    __shared__ int lh[NB];
    for (int i = threadIdx.x; i < NB; i += 256) lh[i] = 0;
    __syncthreads();
    int base = blockIdx.x * EPB;
#pragma unroll
    for (int j = 0; j < EPB / 256; ++j) {
        int e = base + j * 256 + threadIdx.x;
        if (e < N_EDGES) atomicAdd(&lh[dst[e] >> BSH], 1);
    }
    __syncthreads();
    for (int i = threadIdx.x; i < NB; i += 256)
        gh[i * NBLK + blockIdx.x] = lh[i];
}

// ---- pass B: per-bucket exclusive scan of gh across blocks + totals -----
__global__ __launch_bounds__(256) void bucket_scan_kernel(
    int* __restrict__ gh, int* __restrict__ btot) {
    int b = blockIdx.x;
    int t = threadIdx.x;
    __shared__ int ssum[256];
    int v[7];
    int base = t * 7;
    int s = 0;
#pragma unroll
    for (int j = 0; j < 7; ++j) {
        int idx = base + j;
        int val = (idx < NBLK) ? gh[b * NBLK + idx] : 0;
        v[j] = s;
        s += val;
    }
    ssum[t] = s;
    __syncthreads();
    for (int o = 1; o < 256; o <<= 1) {
        int val = (t >= o) ? ssum[t - o] : 0;
        __syncthreads();
        ssum[t] += val;
        __syncthreads();
    }
    int texcl = ssum[t] - s;
#pragma unroll
    for (int j = 0; j < 7; ++j) {
        int idx = base + j;
        if (idx < NBLK) gh[b * NBLK + idx] = texcl + v[j];
    }
    if (t == 255) btot[b] = ssum[255];
}

// ---- pass C: scan bucket totals -> bucket bases (bbase[NB] = N_EDGES) ---
__global__ void base_scan_kernel(const int* __restrict__ btot,
                                 int* __restrict__ bbase) {
    int acc = 0;
    for (int i = 0; i < NB; ++i) { bbase[i] = acc; acc += btot[i]; }
    bbase[NB] = acc;
}

// ---- pass D: place (src,dst) pairs into bucket-sorted tmp ---------------
__global__ __launch_bounds__(256) void bucket_place_kernel(
    const int* __restrict__ src, const int* __restrict__ dst,
    const int* __restrict__ gh, const int* __restrict__ bbase,
    uint2* __restrict__ tmp) {
    __shared__ int cur[NB];
    for (int i = threadIdx.x; i < NB; i += 256)
        cur[i] = bbase[i] + gh[i * NBLK + blockIdx.x];
    __syncthreads();
    int base = blockIdx.x * EPB;
#pragma unroll
    for (int j = 0; j < EPB / 256; ++j) {
        int e = base + j * 256 + threadIdx.x;
        if (e < N_EDGES) {
            int d = dst[e];
            int slot = atomicAdd(&cur[d >> BSH], 1);
            tmp[slot] = make_uint2((unsigned)src[e], (unsigned)d);
        }
    }
}

// ---- aggregation in LDS: one block per bucket ---------------------------
// 8 lanes per edge (float4 per lane); ds_add_f32 into padded acc[256][33]
// (bank = (row + 4q + i) % 32 -> spread). cnt via lane q==0.
__global__ __launch_bounds__(256) void agg_mean_kernel(
    const float* __restrict__ feat, const uint2* __restrict__ tmp,
    const int* __restrict__ bbase, float* __restrict__ meanout) {
    __shared__ float acc[BKN * ACCS];
    __shared__ float cnt[BKN];
    for (int i = threadIdx.x; i < BKN * ACCS; i += 256) acc[i] = 0.f;
    for (int i = threadIdx.x; i < BKN; i += 256) cnt[i] = 0.f;
    __syncthreads();
    int b = blockIdx.x;
    int start = bbase[b], end = bbase[b + 1];
    int g = threadIdx.x >> 3;
    int q = threadIdx.x & 7;
    for (int i = start + g; i < end; i += 32) {
        uint2 p = tmp[i];
        float4 v = ((const float4*)&feat[(size_t)p.x * 32])[q];
        int a = (int)(p.y & (BKN - 1)) * ACCS + q * 4;
        atomicAdd(&acc[a + 0], v.x);
        atomicAdd(&acc[a + 1], v.y);
        atomicAdd(&acc[a + 2], v.z);
        atomicAdd(&acc[a + 3], v.w);
        if (q == 0) atomicAdd(&cnt[p.y & (BKN - 1)], 1.0f);
    }
    __syncthreads();
    int nbase = b << BSH;
    for (int rr = g; rr < BKN; rr += 32) {
        int n = nbase + rr;
        if (n < N_NODES) {
            float inv = 1.0f / fmaxf(cnt[rr], 1.0f);
            int a = rr * ACCS + q * 4;
            ((float4*)&meanout[(size_t)n * 32])[q] =
                make_float4(acc[a] * inv, acc[a + 1] * inv,
                            acc[a + 2] * inv, acc[a + 3] * inv);
        }
    }
}

// same, but finalizes: out = acc/cnt + out (out pre-filled with root term r)
__global__ __launch_bounds__(256) void agg_final_kernel(
    const float* __restrict__ feat, const uint2* __restrict__ tmp,
    const int* __restrict__ bbase, float* __restrict__ out) {
    __shared__ float acc[BKN * ACCS];
    __shared__ float cnt[BKN];
    for (int i = threadIdx.x; i < BKN * ACCS; i += 256) acc[i] = 0.f;
    for (int i = threadIdx.x; i < BKN; i += 256) cnt[i] = 0.f;
    __syncthreads();
    int b = blockIdx.x;
    int start = bbase[b], end = bbase[b + 1];
    int g = threadIdx.x >> 3;
    int q = threadIdx.x & 7;
    for (int i = start + g; i < end; i += 32) {
        uint2 p = tmp[i];
        float4 v = ((const float4*)&feat[(size_t)p.x * 32])[q];
        int a = (int)(p.y & (BKN - 1)) * ACCS + q * 4;
        atomicAdd(&acc[a + 0], v.x);
        atomicAdd(&acc[a + 1], v.y);
        atomicAdd(&acc[a + 2], v.z);
        atomicAdd(&acc[a + 3], v.w);
        if (q == 0) atomicAdd(&cnt[p.y & (BKN - 1)], 1.0f);
    }
    __syncthreads();
    int nbase = b << BSH;
    for (int rr = g; rr < BKN; rr += 32) {
        int n = nbase + rr;
        if (n < N_NODES) {
            float inv = 1.0f / fmaxf(cnt[rr], 1.0f);
            int a = rr * ACCS + q * 4;
            float4 rv = ((const float4*)&out[(size_t)n * 32])[q];
            ((float4*)&out[(size_t)n * 32])[q] =
                make_float4(acc[a] * inv + rv.x, acc[a + 1] * inv + rv.y,
                            acc[a + 2] * inv + rv.z, acc[a + 3] * inv + rv.w);
        }
    }
}

// ---- per-node dense transform: 4 threads/node, conflict-free LDS --------
// (unchanged from round 6 except r goes straight into d_out)
#define W2S 36
__global__ __launch_bounds__(256) void node_transform_kernel(
    const float* __restrict__ x, const float* __restrict__ mean1,
    const float* __restrict__ W1l, const float* __restrict__ W1r,
    const float* __restrict__ b1, const float* __restrict__ W2l,
    const float* __restrict__ W2r, const float* __restrict__ b2,
    float* __restrict__ t, float* __restrict__ r)
{
    __shared__ float sW1l[HID_C * IN_C];     // [j][c]
    __shared__ float sW1r[HID_C * IN_C];
    __shared__ float sW2lT[HID_C * W2S];     // [j][k], stride 36
    __shared__ float sW2rT[HID_C * W2S];
    __shared__ float sb1[HID_C];
    __shared__ float sb2[OUT_C];

    for (int i = threadIdx.x; i < HID_C * IN_C; i += 256) {
        sW1l[i] = W1l[i];
        sW1r[i] = W1r[i];
    }
    for (int i = threadIdx.x; i < OUT_C * HID_C; i += 256) {
        int k = i >> 6;
        int j = i & 63;
        sW2lT[j * W2S + k] = W2l[i];
        sW2rT[j * W2S + k] = W2r[i];
    }
    if (threadIdx.x < HID_C) sb1[threadIdx.x] = b1[threadIdx.x];
    if (threadIdx.x < OUT_C) sb2[threadIdx.x] = b2[threadIdx.x];
    __syncthreads();

    int sub = threadIdx.x & 3;
    int n = blockIdx.x * 64 + (threadIdx.x >> 2);
    bool valid = n < N_NODES;
    int c0 = sub * 8;
    int k0 = sub * 8;

    float4 xq0, xq1, mq0, mq1;
    if (valid) {
        const float4* xp = (const float4*)&x[(long long)n * IN_C + c0];
        const float4* mp = (const float4*)&mean1[(long long)n * IN_C + c0];
        xq0 = xp[0]; xq1 = xp[1];
        mq0 = mp[0]; mq1 = mp[1];
    } else {
        xq0 = xq1 = mq0 = mq1 = make_float4(0.f, 0.f, 0.f, 0.f);
    }

    float tacc[8], racc[8];
#pragma unroll
    for (int i = 0; i < 8; ++i) { tacc[i] = 0.f; racc[i] = sb2[k0 + i]; }

#pragma unroll 8
    for (int j = 0; j < HID_C; ++j) {
        const float4* wl = (const float4*)&sW1l[j * IN_C + c0];
        const float4* wr = (const float4*)&sW1r[j * IN_C + c0];
        float4 l0 = wl[0], l1 = wl[1];
        float4 r0 = wr[0], r1 = wr[1];
        float pl = mq0.x * l0.x + mq0.y * l0.y + mq0.z * l0.z + mq0.w * l0.w
                 + mq1.x * l1.x + mq1.y * l1.y + mq1.z * l1.z + mq1.w * l1.w;
        float pr = xq0.x * r0.x + xq0.y * r0.y + xq0.z * r0.z + xq0.w * r0.w
                 + xq1.x * r1.x + xq1.y * r1.y + xq1.z * r1.z + xq1.w * r1.w;
        float p = pl + pr;
        p += __shfl_xor(p, 1, 64);
        p += __shfl_xor(p, 2, 64);
        float hj = fmaxf(p + sb1[j], 0.0f);

        const float4* w2l = (const float4*)&sW2lT[j * W2S + k0];
        const float4* w2r = (const float4*)&sW2rT[j * W2S + k0];
        float4 a0 = w2l[0], a1 = w2l[1];
        float4 c0v = w2r[0], c1v = w2r[1];
        tacc[0] += hj * a0.x; tacc[1] += hj * a0.y;
        tacc[2] += hj * a0.z; tacc[3] += hj * a0.w;
        tacc[4] += hj * a1.x; tacc[5] += hj * a1.y;
        tacc[6] += hj * a1.z; tacc[7] += hj * a1.w;
        racc[0] += hj * c0v.x; racc[1] += hj * c0v.y;
        racc[2] += hj * c0v.z; racc[3] += hj * c0v.w;
        racc[4] += hj * c1v.x; racc[5] += hj * c1v.y;
        racc[6] += hj * c1v.z; racc[7] += hj * c1v.w;
    }

    if (valid) {
        float4* tp = (float4*)&t[(long long)n * OUT_C + k0];
        float4* rp = (float4*)&r[(long long)n * OUT_C + k0];
        tp[0] = make_float4(tacc[0], tacc[1], tacc[2], tacc[3]);
        tp[1] = make_float4(tacc[4], tacc[5], tacc[6], tacc[7]);
        rp[0] = make_float4(racc[0], racc[1], racc[2], racc[3]);
        rp[1] = make_float4(racc[4], racc[5], racc[6], racc[7]);
    }
}

// ---- launch -------------------------------------------------------------

extern "C" void kernel_launch(void* const* d_in, const int* in_sizes, int n_in,
                              void* d_out, int out_size, void* d_ws, size_t ws_size,
                              hipStream_t stream) {
    const float* x   = (const float*)d_in[0];
    const float* W1l = (const float*)d_in[1];
    const float* W1r = (const float*)d_in[2];
    const float* b1  = (const float*)d_in[3];
    const float* W2l = (const float*)d_in[4];
    const float* W2r = (const float*)d_in[5];
    const float* b2  = (const float*)d_in[6];
    const int*   ei  = (const int*)d_in[7];   // [2, N_EDGES]
    const int* src = ei;
    const int* dst = ei + N_EDGES;

    char* ws = (char*)d_ws;
    int*   gh    = (int*)ws;                 ws += (size_t)NB * NBLK * 4;
    int*   btot  = (int*)ws;                 ws += (size_t)(NB + 8) * 4;
    int*   bbase = (int*)ws;                 ws += (size_t)(NB + 8) * 4;
    uint2* tmp   = (uint2*)ws;               ws += (size_t)N_EDGES * 8;
    float* mean1 = (float*)ws;               ws += (size_t)N_NODES * IN_C * 4;
    float* t     = (float*)ws;               ws += (size_t)N_NODES * OUT_C * 4;
    float* out   = (float*)d_out;            // root term r written here directly

    dim3 blk(256);

    bucket_hist_kernel<<<NBLK, blk, 0, stream>>>(dst, gh);
    bucket_scan_kernel<<<NB, blk, 0, stream>>>(gh, btot);
    base_scan_kernel<<<1, 1, 0, stream>>>(btot, bbase);
    bucket_place_kernel<<<NBLK, blk, 0, stream>>>(src, dst, gh, bbase, tmp);

    agg_mean_kernel<<<NB, blk, 0, stream>>>(x, tmp, bbase, mean1);
    node_transform_kernel<<<(N_NODES + 63) / 64, blk, 0, stream>>>(
        x, mean1, W1l, W1r, b1, W2l, W2r, b2, t, out);
    agg_final_kernel<<<NB, blk, 0, stream>>>(t, tmp, bbase, out);
}

// Round 8
// 212.140 us; speedup vs baseline: 3.8297x; 3.8297x over previous
//
#include <hip/hip_runtime.h>

#define N_NODES 100000
#define N_EDGES 1600000
#define IN_C 32
#define HID_C 64
#define OUT_C 32

#define EPB 1024                                 // edges per hist/place block
#define NBLK ((N_EDGES + EPB - 1) / EPB)         // 1563
#define BSH 8                                    // 256 nodes per bucket
#define BKN (1 << BSH)
#define NB ((N_NODES + BKN - 1) / BKN)           // 391

// ---- pass A: per-block bucket histogram (LDS only; no global atomics) ---
__global__ __launch_bounds__(256) void bucket_hist_kernel(
    const int* __restrict__ dst, int* __restrict__ gh) {
    __shared__ int lh[NB];
    for (int i = threadIdx.x; i < NB; i += 256) lh[i] = 0;
    __syncthreads();
    int base = blockIdx.x * EPB;
#pragma unroll
    for (int j = 0; j < EPB / 256; ++j) {
        int e = base + j * 256 + threadIdx.x;
        if (e < N_EDGES) atomicAdd(&lh[dst[e] >> BSH], 1);
    }
    __syncthreads();
    for (int i = threadIdx.x; i < NB; i += 256)
        gh[i * NBLK + blockIdx.x] = lh[i];
}

// ---- pass B: per-bucket exclusive scan of gh across blocks + totals -----
__global__ __launch_bounds__(256) void bucket_scan_kernel(
    int* __restrict__ gh, int* __restrict__ btot) {
    int b = blockIdx.x;
    int t = threadIdx.x;
    __shared__ int ssum[256];
    int v[7];
    int base = t * 7;
    int s = 0;
#pragma unroll
    for (int j = 0; j < 7; ++j) {
        int idx = base + j;
        int val = (idx < NBLK) ? gh[b * NBLK + idx] : 0;
        v[j] = s;
        s += val;
    }
    ssum[t] = s;
    __syncthreads();
    for (int o = 1; o < 256; o <<= 1) {
        int val = (t >= o) ? ssum[t - o] : 0;
        __syncthreads();
        ssum[t] += val;
        __syncthreads();
    }
    int texcl = ssum[t] - s;
#pragma unroll
    for (int j = 0; j < 7; ++j) {
        int idx = base + j;
        if (idx < NBLK) gh[b * NBLK + idx] = texcl + v[j];
    }
    if (t == 255) btot[b] = ssum[255];
}

// ---- pass C: scan bucket totals -> bucket bases (bbase[NB] = N_EDGES) ---
__global__ void base_scan_kernel(const int* __restrict__ btot,
                                 int* __restrict__ bbase) {
    int acc = 0;
    for (int i = 0; i < NB; ++i) { bbase[i] = acc; acc += btot[i]; }
    bbase[NB] = acc;
}

// ---- pass D: place (src,dst) pairs into bucket-sorted tmp ---------------
__global__ __launch_bounds__(256) void bucket_place_kernel(
    const int* __restrict__ src, const int* __restrict__ dst,
    const int* __restrict__ gh, const int* __restrict__ bbase,
    uint2* __restrict__ tmp) {
    __shared__ int cur[NB];
    for (int i = threadIdx.x; i < NB; i += 256)
        cur[i] = bbase[i] + gh[i * NBLK + blockIdx.x];
    __syncthreads();
    int base = blockIdx.x * EPB;
#pragma unroll
    for (int j = 0; j < EPB / 256; ++j) {
        int e = base + j * 256 + threadIdx.x;
        if (e < N_EDGES) {
            int d = dst[e];
            int slot = atomicAdd(&cur[d >> BSH], 1);
            tmp[slot] = make_uint2((unsigned)src[e], (unsigned)d);
        }
    }
}

// ---- pass E: per-bucket counts + rowptr + perm (all LDS, no global atomics)
__global__ __launch_bounds__(512) void count_place_kernel(
    const uint2* __restrict__ tmp, const int* __restrict__ bbase,
    int* __restrict__ counts, int* __restrict__ rowptr,
    int* __restrict__ perm) {
    __shared__ int lcnt[BKN];
    __shared__ int sscan[BKN];
    __shared__ int cur[BKN];
    int b = blockIdx.x;
    int tid = threadIdx.x;
    int start = bbase[b], end = bbase[b + 1];
    if (tid < BKN) lcnt[tid] = 0;
    __syncthreads();
    for (int i = start + tid; i < end; i += 512)
        atomicAdd(&lcnt[tmp[i].y & (BKN - 1)], 1);
    __syncthreads();
    if (tid < BKN) sscan[tid] = lcnt[tid];
    __syncthreads();
    for (int o = 1; o < BKN; o <<= 1) {
        int v = 0;
        if (tid < BKN && tid >= o) v = sscan[tid - o];
        __syncthreads();
        if (tid < BKN) sscan[tid] += v;
        __syncthreads();
    }
    if (tid < BKN) {
        int excl = sscan[tid] - lcnt[tid] + start;
        cur[tid] = excl;
        int n = (b << BSH) + tid;
        if (n < N_NODES) { rowptr[n] = excl; counts[n] = lcnt[tid]; }
    }
    __syncthreads();
    for (int i = start + tid; i < end; i += 512) {
        uint2 p = tmp[i];
        int slot = atomicAdd(&cur[p.y & (BKN - 1)], 1);
        perm[slot] = (int)p.x;
    }
}

// ---- gathers: one wave per node, 8 edges x float4 in flight -------------
__global__ __launch_bounds__(256) void gather_mean_kernel(
    const float* __restrict__ feat, const int* __restrict__ rowptr,
    const int* __restrict__ counts, const int* __restrict__ perm,
    float* __restrict__ meanout) {
    int lane = threadIdx.x & 63;
    int wid = threadIdx.x >> 6;
    int n = blockIdx.x * 4 + wid;
    if (n >= N_NODES) return;
    int g = lane >> 3;
    int q = lane & 7;
    int start = rowptr[n];
    int cnt = counts[n];
    int end = start + cnt;
    float4 acc = make_float4(0.f, 0.f, 0.f, 0.f);
    for (int i = start + g; i < end; i += 8) {
        int idx = perm[i];
        float4 v = ((const float4*)&feat[(long long)idx * 32])[q];
        acc.x += v.x; acc.y += v.y; acc.z += v.z; acc.w += v.w;
    }
#pragma unroll
    for (int off = 8; off < 64; off <<= 1) {
        acc.x += __shfl_xor(acc.x, off, 64);
        acc.y += __shfl_xor(acc.y, off, 64);
        acc.z += __shfl_xor(acc.z, off, 64);
        acc.w += __shfl_xor(acc.w, off, 64);
    }
    if (g == 0) {
        float inv = 1.0f / fmaxf((float)cnt, 1.0f);
        ((float4*)&meanout[(long long)n * 32])[q] =
            make_float4(acc.x * inv, acc.y * inv, acc.z * inv, acc.w * inv);
    }
}

__global__ __launch_bounds__(256) void gather_final_kernel(
    const float* __restrict__ t, const int* __restrict__ rowptr,
    const int* __restrict__ counts, const int* __restrict__ perm,
    const float* __restrict__ r, float* __restrict__ out) {
    int lane = threadIdx.x & 63;
    int wid = threadIdx.x >> 6;
    int n = blockIdx.x * 4 + wid;
    if (n >= N_NODES) return;
    int g = lane >> 3;
    int q = lane & 7;
    int start = rowptr[n];
    int cnt = counts[n];
    int end = start + cnt;
    float4 acc = make_float4(0.f, 0.f, 0.f, 0.f);
    for (int i = start + g; i < end; i += 8) {
        int idx = perm[i];
        float4 v = ((const float4*)&t[(long long)idx * 32])[q];
        acc.x += v.x; acc.y += v.y; acc.z += v.z; acc.w += v.w;
    }
#pragma unroll
    for (int off = 8; off < 64; off <<= 1) {
        acc.x += __shfl_xor(acc.x, off, 64);
        acc.y += __shfl_xor(acc.y, off, 64);
        acc.z += __shfl_xor(acc.z, off, 64);
        acc.w += __shfl_xor(acc.w, off, 64);
    }
    if (g == 0) {
        float inv = 1.0f / fmaxf((float)cnt, 1.0f);
        float4 rv = ((const float4*)&r[(long long)n * 32])[q];
        ((float4*)&out[(long long)n * 32])[q] =
            make_float4(acc.x * inv + rv.x, acc.y * inv + rv.y,
                        acc.z * inv + rv.z, acc.w * inv + rv.w);
    }
}

// ---- per-node dense transform: 4 threads/node, conflict-free LDS --------
#define W2S 36
__global__ __launch_bounds__(256) void node_transform_kernel(
    const float* __restrict__ x, const float* __restrict__ mean1,
    const float* __restrict__ W1l, const float* __restrict__ W1r,
    const float* __restrict__ b1, const float* __restrict__ W2l,
    const float* __restrict__ W2r, const float* __restrict__ b2,
    float* __restrict__ t, float* __restrict__ r)
{
    __shared__ float sW1l[HID_C * IN_C];     // [j][c]
    __shared__ float sW1r[HID_C * IN_C];
    __shared__ float sW2lT[HID_C * W2S];     // [j][k], stride 36
    __shared__ float sW2rT[HID_C * W2S];
    __shared__ float sb1[HID_C];
    __shared__ float sb2[OUT_C];

    for (int i = threadIdx.x; i < HID_C * IN_C; i += 256) {
        sW1l[i] = W1l[i];
        sW1r[i] = W1r[i];
    }
    for (int i = threadIdx.x; i < OUT_C * HID_C; i += 256) {
        int k = i >> 6;
        int j = i & 63;
        sW2lT[j * W2S + k] = W2l[i];
        sW2rT[j * W2S + k] = W2r[i];
    }
    if (threadIdx.x < HID_C) sb1[threadIdx.x] = b1[threadIdx.x];
    if (threadIdx.x < OUT_C) sb2[threadIdx.x] = b2[threadIdx.x];
    __syncthreads();

    int sub = threadIdx.x & 3;
    int n = blockIdx.x * 64 + (threadIdx.x >> 2);
    bool valid = n < N_NODES;
    int c0 = sub * 8;
    int k0 = sub * 8;

    float4 xq0, xq1, mq0, mq1;
    if (valid) {
        const float4* xp = (const float4*)&x[(long long)n * IN_C + c0];
        const float4* mp = (const float4*)&mean1[(long long)n * IN_C + c0];
        xq0 = xp[0]; xq1 = xp[1];
        mq0 = mp[0]; mq1 = mp[1];
    } else {
        xq0 = xq1 = mq0 = mq1 = make_float4(0.f, 0.f, 0.f, 0.f);
    }

    float tacc[8], racc[8];
#pragma unroll
    for (int i = 0; i < 8; ++i) { tacc[i] = 0.f; racc[i] = sb2[k0 + i]; }

#pragma unroll 8
    for (int j = 0; j < HID_C; ++j) {
        const float4* wl = (const float4*)&sW1l[j * IN_C + c0];
        const float4* wr = (const float4*)&sW1r[j * IN_C + c0];
        float4 l0 = wl[0], l1 = wl[1];
        float4 r0 = wr[0], r1 = wr[1];
        float pl = mq0.x * l0.x + mq0.y * l0.y + mq0.z * l0.z + mq0.w * l0.w
                 + mq1.x * l1.x + mq1.y * l1.y + mq1.z * l1.z + mq1.w * l1.w;
        float pr = xq0.x * r0.x + xq0.y * r0.y + xq0.z * r0.z + xq0.w * r0.w
                 + xq1.x * r1.x + xq1.y * r1.y + xq1.z * r1.z + xq1.w * r1.w;
        float p = pl + pr;
        p += __shfl_xor(p, 1, 64);
        p += __shfl_xor(p, 2, 64);
        float hj = fmaxf(p + sb1[j], 0.0f);

        const float4* w2l = (const float4*)&sW2lT[j * W2S + k0];
        const float4* w2r = (const float4*)&sW2rT[j * W2S + k0];
        float4 a0 = w2l[0], a1 = w2l[1];
        float4 c0v = w2r[0], c1v = w2r[1];
        tacc[0] += hj * a0.x; tacc[1] += hj * a0.y;
        tacc[2] += hj * a0.z; tacc[3] += hj * a0.w;
        tacc[4] += hj * a1.x; tacc[5] += hj * a1.y;
        tacc[6] += hj * a1.z; tacc[7] += hj * a1.w;
        racc[0] += hj * c0v.x; racc[1] += hj * c0v.y;
        racc[2] += hj * c0v.z; racc[3] += hj * c0v.w;
        racc[4] += hj * c1v.x; racc[5] += hj * c1v.y;
        racc[6] += hj * c1v.z; racc[7] += hj * c1v.w;
    }

    if (valid) {
        float4* tp = (float4*)&t[(long long)n * OUT_C + k0];
        float4* rp = (float4*)&r[(long long)n * OUT_C + k0];
        tp[0] = make_float4(tacc[0], tacc[1], tacc[2], tacc[3]);
        tp[1] = make_float4(tacc[4], tacc[5], tacc[6], tacc[7]);
        rp[0] = make_float4(racc[0], racc[1], racc[2], racc[3]);
        rp[1] = make_float4(racc[4], racc[5], racc[6], racc[7]);
    }
}

// ---- launch -------------------------------------------------------------

extern "C" void kernel_launch(void* const* d_in, const int* in_sizes, int n_in,
                              void* d_out, int out_size, void* d_ws, size_t ws_size,
                              hipStream_t stream) {
    const float* x   = (const float*)d_in[0];
    const float* W1l = (const float*)d_in[1];
    const float* W1r = (const float*)d_in[2];
    const float* b1  = (const float*)d_in[3];
    const float* W2l = (const float*)d_in[4];
    const float* W2r = (const float*)d_in[5];
    const float* b2  = (const float*)d_in[6];
    const int*   ei  = (const int*)d_in[7];   // [2, N_EDGES]
    const int* src = ei;
    const int* dst = ei + N_EDGES;

    char* ws = (char*)d_ws;
    int*   gh     = (int*)ws;                ws += (size_t)NB * NBLK * 4;
    int*   btot   = (int*)ws;                ws += (size_t)(NB + 8) * 4;
    int*   bbase  = (int*)ws;                ws += (size_t)(NB + 8) * 4;
    int*   counts = (int*)ws;                ws += (size_t)N_NODES * 4;
    int*   rowptr = (int*)ws;                ws += (size_t)N_NODES * 4;
    int*   perm   = (int*)ws;                ws += (size_t)N_EDGES * 4;
    uint2* tmp    = (uint2*)ws;              ws += (size_t)N_EDGES * 8;
    // mean1 aliases tmp: tmp is dead after count_place_kernel; mean1 written after.
    float* mean1  = (float*)tmp;
    float* t      = (float*)ws;              ws += (size_t)N_NODES * OUT_C * 4;
    float* r      = (float*)ws;              ws += (size_t)N_NODES * OUT_C * 4;

    dim3 blk(256);
    int ggrid = (N_NODES + 3) / 4;

    bucket_hist_kernel<<<NBLK, blk, 0, stream>>>(dst, gh);
    bucket_scan_kernel<<<NB, blk, 0, stream>>>(gh, btot);
    base_scan_kernel<<<1, 1, 0, stream>>>(btot, bbase);
    bucket_place_kernel<<<NBLK, blk, 0, stream>>>(src, dst, gh, bbase, tmp);
    count_place_kernel<<<NB, dim3(512), 0, stream>>>(tmp, bbase, counts, rowptr, perm);

    gather_mean_kernel<<<ggrid, blk, 0, stream>>>(x, rowptr, counts, perm, mean1);
    node_transform_kernel<<<(N_NODES + 63) / 64, blk, 0, stream>>>(
        x, mean1, W1l, W1r, b1, W2l, W2r, b2, t, r);
    gather_final_kernel<<<ggrid, blk, 0, stream>>>(t, rowptr, counts, perm, r,
                                                   (float*)d_out);
}